// Round 7
// baseline (33.535 us; speedup 1.0000x reference)
//
#include <hip/hip_runtime.h>

// GradientFusionloss: loss = mean(|grad(gen_y) - max(grad(vis_y), grad(ir))|)
// grad(I) = |sobel_x(I)| + |sobel_y(I)|, zero-padded 3x3 cross-correlation.
// Shapes: vis (32,3,512,512) f32, ir (32,1,512,512) f32, gen (32,3,512,512) f32.
// Only channel 0 of vis/gen is read. Output: 1 fp32 scalar.
//
// R6: R0 structure (ROWS=8, 1024 blocks, two kernels — fused atomic finalize
// proven 30-60us slower in R3/R4; ROWS=4 proven worse in R5). New: x-halo via
// __shfl from neighbor lanes (wave lanes cover contiguous x-tiles) instead of
// 2 scalar loads per row per plane. Scalar halo load only for the 2 wave-edge
// lanes. Cuts L1 cache-line touches ~3x (each 64-lane scalar load touched the
// same 16 lines as the float4).

#define IMG_H 512
#define IMG_W 512
#define BATCH 32
#define ROWS 8                 // rows per thread strip (10/8 row halo)
#define XT (IMG_W / 4)         // 128 x-tiles (4 px each)
#define STRIPS (IMG_H / ROWS)  // 64
#define THREADS 256
#define TOTAL_THREADS (BATCH * STRIPS * XT)     // 262144
#define NBLOCKS (TOTAL_THREADS / THREADS)       // 1024
#define NPIX ((double)BATCH * IMG_H * IMG_W)

struct Row { float l, x, y, z, w, r; };

__device__ __forceinline__ void zero_row(Row& r) {
    r.l = r.x = r.y = r.z = r.w = r.r = 0.0f;
}

// Load a 4-px row chunk; x-halos come from neighbor lanes via shuffle.
// Wave lanes map to contiguous x-tiles, so lane i-1 holds the left 4 px and
// lane i+1 the right 4 px. Only wave-edge lanes (0, 63) fall back to a
// (2-lane-masked) scalar load; image-edge lanes use 0 (zero padding).
__device__ __forceinline__ void load_row(const float* __restrict__ p, int xb,
                                         bool hl, bool hr, int lane, Row& r) {
    float4 v = *reinterpret_cast<const float4*>(p + xb);
    r.x = v.x; r.y = v.y; r.z = v.z; r.w = v.w;
    float l = __shfl_up(v.w, 1);       // lane 0 gets own value (fixed below)
    float rr = __shfl_down(v.x, 1);    // lane 63 gets own value (fixed below)
    if (lane == 0)  l  = hl ? p[xb - 1] : 0.0f;
    if (lane == 63) rr = hr ? p[xb + 4] : 0.0f;
    r.l = l; r.r = rr;
}

// element j of the 6-wide register row, j in [-1, 4]; j is compile-time
__device__ __forceinline__ float gete(const Row& r, int j) {
    switch (j) {
        case -1: return r.l;
        case 0:  return r.x;
        case 1:  return r.y;
        case 2:  return r.z;
        case 3:  return r.w;
        default: return r.r;
    }
}

// |sobel_x| + |sobel_y| at column j of the 4-wide tile (XLA conv = correlation)
__device__ __forceinline__ float sobel_grad(const Row& t, const Row& m, const Row& b, int j) {
    float a  = gete(t, j - 1), bb = gete(t, j), c  = gete(t, j + 1);
    float d  = gete(m, j - 1),                  f  = gete(m, j + 1);
    float g  = gete(b, j - 1), hh = gete(b, j), i2 = gete(b, j + 1);
    float gx = (c - a) + 2.0f * (f - d) + (i2 - g);
    float gy = (a + 2.0f * bb + c) - (g + 2.0f * hh + i2);
    return fabsf(gx) + fabsf(gy);
}

__global__ __launch_bounds__(THREADS)
void grad_loss_kernel(const float* __restrict__ vis, const float* __restrict__ ir,
                      const float* __restrict__ gen, float* __restrict__ partial) {
    int t    = blockIdx.x * THREADS + threadIdx.x;
    int xt   = t & (XT - 1);
    int rest = t >> 7;
    int ys   = rest & (STRIPS - 1);
    int b    = rest >> 6;
    int lane = threadIdx.x & 63;

    const float* pv = vis + (size_t)b * 3 * IMG_H * IMG_W;  // channel 0
    const float* pi = ir  + (size_t)b * IMG_H * IMG_W;
    const float* pg = gen + (size_t)b * 3 * IMG_H * IMG_W;  // channel 0

    int  xb = xt * 4;
    bool hl = (xt != 0), hr = (xt != XT - 1);
    int  y0 = ys * ROWS;

    Row v0, v1, v2, i0, i1, i2r, g0, g1, g2;
    if (y0 == 0) {
        zero_row(v0); zero_row(i0); zero_row(g0);
    } else {
        load_row(pv + (size_t)(y0 - 1) * IMG_W, xb, hl, hr, lane, v0);
        load_row(pi + (size_t)(y0 - 1) * IMG_W, xb, hl, hr, lane, i0);
        load_row(pg + (size_t)(y0 - 1) * IMG_W, xb, hl, hr, lane, g0);
    }
    load_row(pv + (size_t)y0 * IMG_W, xb, hl, hr, lane, v1);
    load_row(pi + (size_t)y0 * IMG_W, xb, hl, hr, lane, i1);
    load_row(pg + (size_t)y0 * IMG_W, xb, hl, hr, lane, g1);

    float acc = 0.0f;
    #pragma unroll
    for (int r = 0; r < ROWS; ++r) {
        int y = y0 + r;
        if (y == IMG_H - 1) {   // wave-uniform (xt varies, ys uniform per wave)
            zero_row(v2); zero_row(i2r); zero_row(g2);
        } else {
            load_row(pv + (size_t)(y + 1) * IMG_W, xb, hl, hr, lane, v2);
            load_row(pi + (size_t)(y + 1) * IMG_W, xb, hl, hr, lane, i2r);
            load_row(pg + (size_t)(y + 1) * IMG_W, xb, hl, hr, lane, g2);
        }
        #pragma unroll
        for (int j = 0; j < 4; ++j) {
            float ggen = sobel_grad(g0, g1, g2, j);
            float gvis = sobel_grad(v0, v1, v2, j);
            float gir  = sobel_grad(i0, i1, i2r, j);
            acc += fabsf(ggen - fmaxf(gvis, gir));
        }
        v0 = v1; v1 = v2;
        i0 = i1; i1 = i2r;
        g0 = g1; g1 = g2;
    }

    // block reduction (fixed order -> deterministic)
    #pragma unroll
    for (int off = 32; off > 0; off >>= 1)
        acc += __shfl_down(acc, off, 64);
    __shared__ float s[THREADS / 64];
    int wid = threadIdx.x >> 6;
    if (lane == 0) s[wid] = acc;
    __syncthreads();
    if (threadIdx.x == 0)
        partial[blockIdx.x] = s[0] + s[1] + s[2] + s[3];
}

__global__ __launch_bounds__(THREADS)
void reduce_kernel(const float* __restrict__ partial, float* __restrict__ out) {
    float acc = 0.0f;
    #pragma unroll
    for (int i = 0; i < NBLOCKS / THREADS; ++i)   // fixed order -> deterministic
        acc += partial[threadIdx.x + i * THREADS];
    #pragma unroll
    for (int off = 32; off > 0; off >>= 1)
        acc += __shfl_down(acc, off, 64);
    __shared__ float s[THREADS / 64];
    int lane = threadIdx.x & 63, wid = threadIdx.x >> 6;
    if (lane == 0) s[wid] = acc;
    __syncthreads();
    if (threadIdx.x == 0)
        out[0] = (float)((s[0] + s[1] + s[2] + s[3]) * (1.0 / NPIX));
}

extern "C" void kernel_launch(void* const* d_in, const int* in_sizes, int n_in,
                              void* d_out, int out_size, void* d_ws, size_t ws_size,
                              hipStream_t stream) {
    const float* vis = (const float*)d_in[0];
    const float* ir  = (const float*)d_in[1];
    const float* gen = (const float*)d_in[2];
    float* out       = (float*)d_out;
    float* partial   = (float*)d_ws;   // NBLOCKS floats = 4 KiB

    grad_loss_kernel<<<NBLOCKS, THREADS, 0, stream>>>(vis, ir, gen, partial);
    reduce_kernel<<<1, THREADS, 0, stream>>>(partial, out);
}

// Round 8
// 26.062 us; speedup vs baseline: 1.2868x; 1.2868x over previous
//
#include <hip/hip_runtime.h>

// GradientFusionloss: loss = mean(|grad(gen_y) - max(grad(vis_y), grad(ir))|)
// grad(I) = |sobel_x(I)| + |sobel_y(I)|, zero-padded 3x3 cross-correlation.
// Shapes: vis (32,3,512,512) f32, ir (32,1,512,512) f32, gen (32,3,512,512) f32.
// Only channel 0 of vis/gen is read. Output: 1 fp32 scalar.
//
// R7 = R0 (proven best: ROWS=8, 1024 blocks, two kernels, scalar halo loads)
// + distance-1 software prefetch: issue row y+2's 9 loads BEFORE computing
// row y, so each iteration's ~300cy of VALU hides the next row's load
// latency (R0 drained vmcnt every iteration -> latency-bound, VALUBusy 8%).
// Bottom-edge zero row folds into the prefetch guard (wave-uniform branch).
// Failed alternatives (do not revisit): fused atomic finalize (R3/R4, same-
// line RMW storm +30-60us), ROWS=16 (R1, occupancy collapse), ROWS=4 (R5,
// +50% loads), shfl halos (R6, DS latency on critical path), VGPR caps (R2,
// 97MB spill).

#define IMG_H 512
#define IMG_W 512
#define BATCH 32
#define ROWS 8                 // rows per thread strip (10/8 row halo)
#define XT (IMG_W / 4)         // 128 x-tiles (4 px each)
#define STRIPS (IMG_H / ROWS)  // 64
#define THREADS 256
#define TOTAL_THREADS (BATCH * STRIPS * XT)     // 262144
#define NBLOCKS (TOTAL_THREADS / THREADS)       // 1024
#define NPIX ((double)BATCH * IMG_H * IMG_W)

struct Row { float l, x, y, z, w, r; };

__device__ __forceinline__ void zero_row(Row& r) {
    r.l = r.x = r.y = r.z = r.w = r.r = 0.0f;
}

__device__ __forceinline__ void load_row(const float* __restrict__ p, int xb,
                                         bool hl, bool hr, Row& r) {
    float4 v = *reinterpret_cast<const float4*>(p + xb);
    r.x = v.x; r.y = v.y; r.z = v.z; r.w = v.w;
    r.l = hl ? p[xb - 1] : 0.0f;   // L1-hit: line fetched by neighbor lane's float4
    r.r = hr ? p[xb + 4] : 0.0f;
}

// element j of the 6-wide register row, j in [-1, 4]; j is compile-time
__device__ __forceinline__ float gete(const Row& r, int j) {
    switch (j) {
        case -1: return r.l;
        case 0:  return r.x;
        case 1:  return r.y;
        case 2:  return r.z;
        case 3:  return r.w;
        default: return r.r;
    }
}

// |sobel_x| + |sobel_y| at column j of the 4-wide tile (XLA conv = correlation)
__device__ __forceinline__ float sobel_grad(const Row& t, const Row& m, const Row& b, int j) {
    float a  = gete(t, j - 1), bb = gete(t, j), c  = gete(t, j + 1);
    float d  = gete(m, j - 1),                  f  = gete(m, j + 1);
    float g  = gete(b, j - 1), hh = gete(b, j), i2 = gete(b, j + 1);
    float gx = (c - a) + 2.0f * (f - d) + (i2 - g);
    float gy = (a + 2.0f * bb + c) - (g + 2.0f * hh + i2);
    return fabsf(gx) + fabsf(gy);
}

__global__ __launch_bounds__(THREADS)
void grad_loss_kernel(const float* __restrict__ vis, const float* __restrict__ ir,
                      const float* __restrict__ gen, float* __restrict__ partial) {
    int t    = blockIdx.x * THREADS + threadIdx.x;
    int xt   = t & (XT - 1);
    int rest = t >> 7;
    int ys   = rest & (STRIPS - 1);
    int b    = rest >> 6;

    const float* pv = vis + (size_t)b * 3 * IMG_H * IMG_W;  // channel 0
    const float* pi = ir  + (size_t)b * IMG_H * IMG_W;
    const float* pg = gen + (size_t)b * 3 * IMG_H * IMG_W;  // channel 0

    int  xb = xt * 4;
    bool hl = (xt != 0), hr = (xt != XT - 1);
    int  y0 = ys * ROWS;

    // Rolling window: *m = row y-1, *0 = row y, *1 = row y+1, *n = incoming y+2
    Row vm, vz, v1, vn, im, iz, i1, in_, gm, gz, g1, gn;
    if (y0 == 0) {
        zero_row(vm); zero_row(im); zero_row(gm);
    } else {
        load_row(pv + (size_t)(y0 - 1) * IMG_W, xb, hl, hr, vm);
        load_row(pi + (size_t)(y0 - 1) * IMG_W, xb, hl, hr, im);
        load_row(pg + (size_t)(y0 - 1) * IMG_W, xb, hl, hr, gm);
    }
    load_row(pv + (size_t)y0 * IMG_W, xb, hl, hr, vz);
    load_row(pi + (size_t)y0 * IMG_W, xb, hl, hr, iz);
    load_row(pg + (size_t)y0 * IMG_W, xb, hl, hr, gz);
    // y0+1 <= 505 always valid
    load_row(pv + (size_t)(y0 + 1) * IMG_W, xb, hl, hr, v1);
    load_row(pi + (size_t)(y0 + 1) * IMG_W, xb, hl, hr, i1);
    load_row(pg + (size_t)(y0 + 1) * IMG_W, xb, hl, hr, g1);

    float acc = 0.0f;
    #pragma unroll
    for (int r = 0; r < ROWS; ++r) {
        int y = y0 + r;
        // Prefetch row y+2 (consumed next iteration). Wave-uniform guard;
        // also supplies the zero row below the image bottom.
        if (y + 2 < IMG_H) {
            load_row(pv + (size_t)(y + 2) * IMG_W, xb, hl, hr, vn);
            load_row(pi + (size_t)(y + 2) * IMG_W, xb, hl, hr, in_);
            load_row(pg + (size_t)(y + 2) * IMG_W, xb, hl, hr, gn);
        } else {
            zero_row(vn); zero_row(in_); zero_row(gn);
        }
        // Compute row y from data loaded >= 1 iteration ago (vmcnt counted,
        // prefetch stays in flight).
        #pragma unroll
        for (int j = 0; j < 4; ++j) {
            float ggen = sobel_grad(gm, gz, g1, j);
            float gvis = sobel_grad(vm, vz, v1, j);
            float gir  = sobel_grad(im, iz, i1, j);
            acc += fabsf(ggen - fmaxf(gvis, gir));
        }
        vm = vz; vz = v1; v1 = vn;
        im = iz; iz = i1; i1 = in_;
        gm = gz; gz = g1; g1 = gn;
    }

    // block reduction (fixed order -> deterministic)
    #pragma unroll
    for (int off = 32; off > 0; off >>= 1)
        acc += __shfl_down(acc, off, 64);
    __shared__ float s[THREADS / 64];
    int lane = threadIdx.x & 63, wid = threadIdx.x >> 6;
    if (lane == 0) s[wid] = acc;
    __syncthreads();
    if (threadIdx.x == 0)
        partial[blockIdx.x] = s[0] + s[1] + s[2] + s[3];
}

__global__ __launch_bounds__(THREADS)
void reduce_kernel(const float* __restrict__ partial, float* __restrict__ out) {
    float acc = 0.0f;
    #pragma unroll
    for (int i = 0; i < NBLOCKS / THREADS; ++i)   // fixed order -> deterministic
        acc += partial[threadIdx.x + i * THREADS];
    #pragma unroll
    for (int off = 32; off > 0; off >>= 1)
        acc += __shfl_down(acc, off, 64);
    __shared__ float s[THREADS / 64];
    int lane = threadIdx.x & 63, wid = threadIdx.x >> 6;
    if (lane == 0) s[wid] = acc;
    __syncthreads();
    if (threadIdx.x == 0)
        out[0] = (float)((s[0] + s[1] + s[2] + s[3]) * (1.0 / NPIX));
}

extern "C" void kernel_launch(void* const* d_in, const int* in_sizes, int n_in,
                              void* d_out, int out_size, void* d_ws, size_t ws_size,
                              hipStream_t stream) {
    const float* vis = (const float*)d_in[0];
    const float* ir  = (const float*)d_in[1];
    const float* gen = (const float*)d_in[2];
    float* out       = (float*)d_out;
    float* partial   = (float*)d_ws;   // NBLOCKS floats = 4 KiB

    grad_loss_kernel<<<NBLOCKS, THREADS, 0, stream>>>(vis, ir, gen, partial);
    reduce_kernel<<<1, THREADS, 0, stream>>>(partial, out);
}